// Round 2
// baseline (633.108 us; speedup 1.0000x reference)
//
#include <hip/hip_runtime.h>
#include <hip/hip_bf16.h>
#include <cstdint>
#include <cstddef>

// Problem dims (fixed by reference)
#define BDIM 512
#define SDIM 64
#define DDIM 256
#define D2   512
#define NNODE 100000
#define NM1  99999   // logits columns

typedef short short8 __attribute__((ext_vector_type(8)));
typedef float f32x4 __attribute__((ext_vector_type(4)));

__device__ __forceinline__ unsigned short f2bf(float f) {
  unsigned int u = __float_as_uint(f);
  u += 0x7FFFu + ((u >> 16) & 1u);   // RNE
  return (unsigned short)(u >> 16);
}

// ---------------------------------------------------------------------------
// Kernel 1: fused per-batch prep + 2-layer MLP. The whole chain is row-wise:
// av[b,:] -> h1[b,:] = relu(av@W1) -> lasth[b,:] = h1@W2 (bf16).
// One block per batch element; intermediates live in LDS only.
// ---------------------------------------------------------------------------
__global__ __launch_bounds__(256) void fused_mlp(
    const float* __restrict__ emb, const float* __restrict__ W1,
    const float* __restrict__ W2, const float* __restrict__ adj_in,
    const float* __restrict__ adj_out, const float* __restrict__ mask,
    const int* __restrict__ item, const int* __restrict__ alias_,
    unsigned short* __restrict__ lasth) {
  __shared__ float a_in[SDIM], a_out[SDIM];
  __shared__ int it[SDIM];
  __shared__ int s_star;
  __shared__ float av[D2];   // [0:256]=in-agg, [256:512]=out-agg
  __shared__ float h1[D2];
  const int b = blockIdx.x, t = threadIdx.x;
  if (t < SDIM) it[t] = item[b * SDIM + t];
  if (t == 0) {
    float s = 0.f;
    for (int j = 0; j < SDIM; j++) s += mask[b * SDIM + j];
    int rm = (int)s;                       // matches astype(int32)
    s_star = alias_[b * SDIM + rm - 1];
  }
  __syncthreads();
  const int ss = s_star;
  if (t < SDIM) a_in[t] = adj_in[((size_t)b * SDIM + ss) * SDIM + t];
  else if (t < 2 * SDIM) a_out[t - SDIM] = adj_out[((size_t)b * SDIM + ss) * SDIM + (t - SDIM)];
  __syncthreads();
  // Phase A: av row (gathered aggregation), d = t (coalesced across d)
  {
    float ai = 0.f, ao = 0.f;
#pragma unroll 8
    for (int j = 0; j < SDIM; j++) {
      float e = emb[(size_t)it[j] * DDIM + t];
      ai = fmaf(a_in[j], e, ai);
      ao = fmaf(a_out[j], e, ao);
    }
    av[t] = ai;
    av[DDIM + t] = ao;
  }
  __syncthreads();
  // Phase B: h1 = relu(av @ W1); thread t computes cols t and t+256.
  {
    float acc0 = 0.f, acc1 = 0.f;
#pragma unroll 4
    for (int k = 0; k < D2; k++) {
      const float a = av[k];                     // LDS broadcast
      acc0 = fmaf(a, W1[(size_t)k * D2 + t], acc0);
      acc1 = fmaf(a, W1[(size_t)k * D2 + t + 256], acc1);
    }
    h1[t] = fmaxf(acc0, 0.f);
    h1[t + 256] = fmaxf(acc1, 0.f);
  }
  __syncthreads();
  // Phase C: lasth = h1 @ W2 (bf16 out); thread t computes col t.
  {
    float acc = 0.f;
#pragma unroll 4
    for (int k = 0; k < D2; k++)
      acc = fmaf(h1[k], W2[(size_t)k * DDIM + t], acc);
    lasth[(size_t)b * DDIM + t] = f2bf(acc);
  }
}

// ---------------------------------------------------------------------------
// Kernel 2: logits[512, 99999] = lasth(bf16) @ emb[1:]^T  (bf16 MFMA)
// Full-K staging: block stages its 64 emb rows x K=256 ONCE (33.8 KB LDS,
// 4 blocks/CU), one barrier, then each wave independently sweeps M=512 in
// two 64-row chunks with A read from global (L2-resident, 256 KB).
// Fused epilogue: per-row sum of exp(logit) -> atomicAdd into rse[512].
// ---------------------------------------------------------------------------
#define LDB 264   // shorts per staged emb row (256 + 8 pad)
__global__ __launch_bounds__(256) void logits_gemm(
    const unsigned short* __restrict__ Abf,  // [512,256] bf16
    const float* __restrict__ emb,           // [100000,256] f32
    float* __restrict__ out,                 // d_out: [0]=loss, [1..]=logits
    float* __restrict__ rse) {               // [512] running sum-exp
  __shared__ short Bs[64 * LDB];             // 33792 B
  const int t = threadIdx.x;
  const int nbase = blockIdx.x * 64;

  // ---- stage B tile: emb rows nbase+1 .. nbase+64, full K, f32->bf16
#pragma unroll
  for (int pass = 0; pass < 8; ++pass) {
    const int g = pass * 512 + t * 2;        // float4-pair index (0..4094)
    const int row = g >> 6;                  // 0..63
    const int c4 = g & 63;                   // float4 index within row (even)
    int er = nbase + row + 1; if (er > NM1) er = NM1;
    const float* bg = emb + (size_t)er * DDIM + c4 * 4;
    const float4 b0 = ((const float4*)bg)[0];
    const float4 b1 = ((const float4*)bg)[1];
    short8 p;
    p[0] = (short)f2bf(b0.x); p[1] = (short)f2bf(b0.y);
    p[2] = (short)f2bf(b0.z); p[3] = (short)f2bf(b0.w);
    p[4] = (short)f2bf(b1.x); p[5] = (short)f2bf(b1.y);
    p[6] = (short)f2bf(b1.z); p[7] = (short)f2bf(b1.w);
    *(short8*)&Bs[row * LDB + c4 * 4] = p;
  }
  __syncthreads();

  const int w = t >> 6, lane = t & 63;
  const int c = lane & 15, q = lane >> 4;

  // each wave owns M-rows [w*128, w*128+128), processed in 2 chunks of 64
#pragma unroll
  for (int cc = 0; cc < 2; ++cc) {
    const int arow0 = w * 128 + cc * 64;
    f32x4 acc[4][4];
#pragma unroll
    for (int mi = 0; mi < 4; mi++)
#pragma unroll
      for (int ni = 0; ni < 4; ni++) acc[mi][ni] = (f32x4){0.f, 0.f, 0.f, 0.f};

#pragma unroll
    for (int kk = 0; kk < DDIM; kk += 32) {
      short8 afr[4], bfr[4];
#pragma unroll
      for (int mi = 0; mi < 4; mi++)
        afr[mi] = *(const short8*)(Abf + (size_t)(arow0 + mi * 16 + c) * DDIM + kk + q * 8);
#pragma unroll
      for (int ni = 0; ni < 4; ni++)
        bfr[ni] = *(const short8*)&Bs[(ni * 16 + c) * LDB + kk + q * 8];
#pragma unroll
      for (int mi = 0; mi < 4; mi++)
#pragma unroll
        for (int ni = 0; ni < 4; ni++)
          acc[mi][ni] = __builtin_amdgcn_mfma_f32_16x16x32_bf16(
              afr[mi], bfr[ni], acc[mi][ni], 0, 0, 0);
    }

    // epilogue for this 64x64 chunk: store + partial sum-exp per row
#pragma unroll
    for (int mi = 0; mi < 4; mi++) {
#pragma unroll
      for (int r = 0; r < 4; r++) {
        const int grow = arow0 + mi * 16 + q * 4 + r;   // C/D: row=q*4+reg
        float s = 0.f;
#pragma unroll
        for (int ni = 0; ni < 4; ni++) {
          const int col = nbase + ni * 16 + c;          // C/D: col=lane&15
          if (col < NM1) {
            const float v = acc[mi][ni][r];
            out[1 + (size_t)grow * NM1 + col] = v;
            s += __expf(v);
          }
        }
#pragma unroll
        for (int msk = 1; msk < 16; msk <<= 1) s += __shfl_xor(s, msk, 64);
        if (c == 0) atomicAdd(&rse[grow], s);
      }
    }
  }
}

// ---------------------------------------------------------------------------
// Kernel 3: loss = mean_b( log(sum_exp[b]) - logits[b, tar[b]-1] )
// ---------------------------------------------------------------------------
__global__ __launch_bounds__(512) void loss_kernel(
    float* __restrict__ out, const float* __restrict__ rse,
    const int* __restrict__ tar) {
  __shared__ float red[512];
  const int t = threadIdx.x;
  const int tt = tar[t];
  const float lg = out[1 + (size_t)t * NM1 + (tt - 1)];
  red[t] = logf(rse[t]) - lg;
  __syncthreads();
  for (int stride = 256; stride > 0; stride >>= 1) {
    if (t < stride) red[t] += red[t + stride];
    __syncthreads();
  }
  if (t == 0) out[0] = red[0] / (float)BDIM;
}

// ---------------------------------------------------------------------------
extern "C" void kernel_launch(void* const* d_in, const int* in_sizes, int n_in,
                              void* d_out, int out_size, void* d_ws, size_t ws_size,
                              hipStream_t stream) {
  const float* emb     = (const float*)d_in[0];
  const float* W1      = (const float*)d_in[1];
  const float* W2      = (const float*)d_in[2];
  const float* adj_in  = (const float*)d_in[3];
  const float* adj_out = (const float*)d_in[4];
  const float* mask    = (const float*)d_in[5];
  const int*   item    = (const int*)d_in[6];
  const int*   alias_  = (const int*)d_in[7];
  const int*   tar     = (const int*)d_in[8];
  float* out = (float*)d_out;

  char* ws = (char*)d_ws;
  unsigned short* lasth = (unsigned short*)(ws);        // 512*256*2 = 256 KB
  float* rse            = (float*)(ws + 262144);        // 512*4

  hipMemsetAsync(rse, 0, BDIM * sizeof(float), stream);
  fused_mlp<<<BDIM, 256, 0, stream>>>(emb, W1, W2, adj_in, adj_out, mask,
                                      item, alias_, lasth);
  logits_gemm<<<dim3((NM1 + 63) / 64), 256, 0, stream>>>(lasth, emb, out, rse);
  loss_kernel<<<1, 512, 0, stream>>>(out, rse, tar);
}